// Round 16
// baseline (216.611 us; speedup 1.0000x reference)
//
#include <hip/hip_runtime.h>

#define D 64
#define ALPHA 0.5f
#define FXSCALE 16777216.f   // 2^24 fixed-point quantum for degree accumulation
#define CE 2048              // edges per chunk (P3 block)
#define BSH 9                // log2(nodes per bucket)
#define BN 512               // nodes per bucket
#define CAP 9216             // padded bucket capacity (mean 8184, +11.5 sigma)

typedef unsigned long long u64;
typedef unsigned short u16;
typedef unsigned int u32;
typedef float f32x4 __attribute__((ext_vector_type(4)));

static __device__ __forceinline__ u16 f2bf(float f) {
    unsigned u = __float_as_uint(f);
    unsigned r = (u + 0x7fffu + ((u >> 16) & 1u)) >> 16;
    return (u16)r;
}
static __device__ __forceinline__ float bf2f(u16 h) {
    return __uint_as_float(((unsigned)h) << 16);
}
static __device__ __forceinline__ float dinv_of_fx(u32 fx) {
    float s = (float)fx * (1.f / FXSCALE);
    return (s > 0.f) ? rsqrtf(s) : 0.f;
}

// P3 (standalone): in-LDS counting sort of a chunk's 2*CE entries by
// dst-bucket; one global atomicAdd per (chunk,bucket) reserves a run in the
// padded bucket region (base = bucket*CAP + cursor).
// entry u64 = w_bits<<32 | src<<9 | dst_lo9
__global__ __launch_bounds__(512)
void p3_sort_kernel(const int* __restrict__ row, const int* __restrict__ col,
                    const float* __restrict__ w, u32* __restrict__ cursor,
                    u64* __restrict__ ent, int N, int E, int NBUCK) {
    __shared__ u64 ebuf[4096];
    __shared__ u16 ebkt[4096];
    __shared__ u32 hcnt[512], hstart[512], hoff[512], hbase[512];
    __shared__ int s[512];
    int t = threadIdx.x, ch = blockIdx.x;
    hcnt[t] = 0;
    __syncthreads();
    int e0 = ch * CE, e1 = min(E, e0 + CE);
    for (int e = e0 + t; e < e1; e += 512) {
        atomicAdd(&hcnt[(u32)row[e] >> BSH], 1u);
        atomicAdd(&hcnt[(u32)(N + col[e]) >> BSH], 1u);
    }
    __syncthreads();
    int v = (int)hcnt[t];
    s[t] = v;
    __syncthreads();
    for (int off = 1; off < 512; off <<= 1) {
        int u = (t >= off) ? s[t - off] : 0;
        __syncthreads();
        s[t] += u;
        __syncthreads();
    }
    hstart[t] = (u32)(s[t] - v);
    hoff[t]   = (u32)(s[t] - v);
    u32 myb = 0;
    if (t < NBUCK && v > 0) myb = atomicAdd(&cursor[t], (u32)v);
    hbase[t] = myb;
    __syncthreads();
    for (int e = e0 + t; e < e1; e += 512) {
        int r = row[e], c = col[e];
        u32 wb = __float_as_uint(w[e]);
        u32 b1 = (u32)r >> BSH;
        u64 q1 = ((u64)wb << 32) | ((u32)c << BSH) | ((u32)r & (BN - 1));
        u32 p1 = atomicAdd(&hoff[b1], 1u);
        ebuf[p1] = q1; ebkt[p1] = (u16)b1;
        u32 d2 = (u32)(N + c);
        u32 b2 = d2 >> BSH;
        u64 q2 = ((u64)wb << 32) | ((u32)r << BSH) | (d2 & (BN - 1));
        u32 p2 = atomicAdd(&hoff[b2], 1u);
        ebuf[p2] = q2; ebkt[p2] = (u16)b2;
    }
    __syncthreads();
    int nent = 2 * (e1 - e0);
    for (int p = t; p < nent; p += 512) {
        u32 bb = ebkt[p];
        u32 local = hbase[bb] + (u32)p - hstart[bb];
        if (local < CAP)   // overflow guard (statistically impossible)
            ent[(size_t)bb * CAP + local] = ebuf[p];
    }
}

// Fused heterogeneous kernel: P4 bucket-build blocks + transform tiles.
//  - P4 role (memory-streaming, VALU-idle): per-bucket node histogram
//    (counts + fixed-point weighted degree), per-node (start,end) -> ptr2,
//    dinv, edata fill. Scatter confined to an L2-resident bucket window.
//  - transform role (pure VALU): y1 = bf16(ALPHA*x@Ws^T), y2 = bf16((1-a)*x@Wd^T).
// Complementary pipes -> fused ~ max, not sum.
// LDS union (u64 slots): P4: cnt[0,256) fx[256,512) pstart[512,768)
// pfill[768,1024) s[1024,1280).  transform: 12864 floats = 6432 u64.
__global__ __launch_bounds__(512)
void p4_transform_kernel(const u64* __restrict__ ent, const u32* __restrict__ cursor,
                         float* __restrict__ dinv, int2* __restrict__ ptr2,
                         float2* __restrict__ edata,
                         const float* __restrict__ x,
                         const float* __restrict__ Ws, const float* __restrict__ Wd,
                         u16* __restrict__ y1, u16* __restrict__ y2,
                         int N, int L, int NBUCK, int NT, int total_blocks) {
    __shared__ u64 smem[6432];
    int b = blockIdx.x;
    int t = threadIdx.x;
    int t_before = (int)(((long long)b * NT) / total_blocks);
    bool is_t = (int)(((long long)(b + 1) * NT) / total_blocks) > t_before;

    if (!is_t) {
        // ---------------- P4 bucket-build role ----------------
        int bk = b - t_before;
        u32* cnt    = (u32*)smem;            // [512]
        u32* fx     = (u32*)(smem + 256);    // [512]
        u32* pstart = (u32*)(smem + 512);    // [512]
        u32* pfill  = (u32*)(smem + 768);    // [512]
        int* s      = (int*)(smem + 1024);   // [512]
        int base0 = bk * CAP;
        int nE = min((int)cursor[bk], CAP);
        cnt[t] = 0; fx[t] = 0;
        __syncthreads();
        for (int i = t; i < nE; i += 512) {
            u64 q = ent[(size_t)base0 + i];
            u32 dlo = (u32)q & (BN - 1);
            float wv = __uint_as_float((u32)(q >> 32));
            atomicAdd(&cnt[dlo], 1u);
            atomicAdd(&fx[dlo], (u32)__float2uint_rn(wv * FXSCALE));
        }
        __syncthreads();
        int v = (int)cnt[t];
        s[t] = v;
        __syncthreads();
        for (int off = 1; off < 512; off <<= 1) {
            int u = (t >= off) ? s[t - off] : 0;
            __syncthreads();
            s[t] += u;
            __syncthreads();
        }
        pstart[t] = (u32)(s[t] - v);
        pfill[t]  = (u32)(s[t] - v);
        int node = bk * BN + t;
        if (node < L) {
            dinv[node] = dinv_of_fx(fx[t]);
            int st = base0 + (int)pstart[t];
            ptr2[node] = make_int2(st, st + v);
        }
        __syncthreads();
        for (int i = t; i < nE; i += 512) {
            u64 q = ent[(size_t)base0 + i];
            u32 dlo = (u32)q & (BN - 1);
            u32 src = ((u32)q) >> BSH;
            float wv = __uint_as_float((u32)(q >> 32));
            u32 pos = atomicAdd(&pfill[dlo], 1u);
            edata[(size_t)base0 + pos] = make_float2(__int_as_float((int)src), wv);
        }
        return;
    }

    // ---------------- transform role (64-row tile, 512 threads) ----------------
    float* xs  = (float*)smem;            // [64][65]
    float* Wt1 = xs + 64 * 65;            // [64][68] (272B row: float4-aligned)
    float* Wt2 = Wt1 + 64 * 68;
    for (int i = t; i < 4096; i += 512) {
        int o = i >> 6, k = i & 63;
        Wt1[k * 68 + o] = Ws[i];
        Wt2[k * 68 + o] = Wd[i];
    }
    int r0 = t_before * 64;
    for (int i = t; i < 4096; i += 512) {
        int r = i >> 6, k = i & 63;
        int gr = r0 + r;
        xs[r * 65 + k] = (gr < N) ? x[(size_t)gr * D + k] : 0.f;
    }
    __syncthreads();
    int ro = t >> 4, co = t & 15;        // ro 0..31 (2 rows each), co 0..15 (4 cols)
    float a1[2][4] = {}, a2[2][4] = {};
#pragma unroll 4
    for (int k = 0; k < 64; ++k) {
        float v0 = xs[(ro * 2 + 0) * 65 + k];
        float v1 = xs[(ro * 2 + 1) * 65 + k];
        float4 b1 = *(const float4*)&Wt1[k * 68 + co * 4];
        float4 b2 = *(const float4*)&Wt2[k * 68 + co * 4];
        a1[0][0] += v0 * b1.x; a1[0][1] += v0 * b1.y; a1[0][2] += v0 * b1.z; a1[0][3] += v0 * b1.w;
        a1[1][0] += v1 * b1.x; a1[1][1] += v1 * b1.y; a1[1][2] += v1 * b1.z; a1[1][3] += v1 * b1.w;
        a2[0][0] += v0 * b2.x; a2[0][1] += v0 * b2.y; a2[0][2] += v0 * b2.z; a2[0][3] += v0 * b2.w;
        a2[1][0] += v1 * b2.x; a2[1][1] += v1 * b2.y; a2[1][2] += v1 * b2.z; a2[1][3] += v1 * b2.w;
    }
#pragma unroll
    for (int i = 0; i < 2; ++i) {
        int gr = r0 + ro * 2 + i;
        if (gr < N) {
            ushort4 o1, o2;
            o1.x = f2bf(a1[i][0] * ALPHA); o1.y = f2bf(a1[i][1] * ALPHA);
            o1.z = f2bf(a1[i][2] * ALPHA); o1.w = f2bf(a1[i][3] * ALPHA);
            o2.x = f2bf(a2[i][0] * (1.f - ALPHA)); o2.y = f2bf(a2[i][1] * (1.f - ALPHA));
            o2.z = f2bf(a2[i][2] * (1.f - ALPHA)); o2.w = f2bf(a2[i][3] * (1.f - ALPHA));
            *(ushort4*)&y1[(size_t)gr * D + co * 4] = o1;
            *(ushort4*)&y2[(size_t)gr * D + co * 4] = o2;
        }
    }
}

// gather: one wave per node; 64 lanes = 4 edge-slots x 16 feature-slots.
// Both directions interleaved (8 independent chains). edata loaded
// NON-TEMPORAL (51 MB stream-once: don't evict reused y lines from L2).
// Per-edge src-side dinv read (800 KB, L2-resident, cached).
__global__ void gather_csr_kernel(const int2* __restrict__ ptr2, const float* __restrict__ dinv,
                                  const float2* __restrict__ ed,
                                  const u16* __restrict__ y1, const u16* __restrict__ y2,
                                  const float* __restrict__ b_src, const float* __restrict__ b_dst,
                                  float* __restrict__ out, int N) {
    int tid = threadIdx.x;
    int lane = tid & 63;
    int node = blockIdx.x * (blockDim.x >> 6) + (tid >> 6);
    if (node >= N) return;
    int g  = lane >> 4;
    int fl = lane & 15;

    int2 pf = ptr2[node];          // fwd segment (y1)
    int2 pb = ptr2[N + node];      // bwd segment (y2)
    int ef = pf.x, ef1 = pf.y;
    int eb = pb.x, eb1 = pb.y;
    const float* __restrict__ dsf = dinv + N;   // fwd src-side dinv
    const float* __restrict__ dsb = dinv;       // bwd src-side dinv
    const u64* __restrict__ edq = (const u64*)ed;

    float f0 = 0.f, f1 = 0.f, f2 = 0.f, f3 = 0.f;
    float b0 = 0.f, b1 = 0.f, b2 = 0.f, b3 = 0.f;

    while (ef < ef1 || eb < eb1) {
        if (ef < ef1) {
            int ea = ef + g, ex = ef + 4 + g, ea2 = ef + 8 + g, ex2 = ef + 12 + g;
            u64 qda = (ea  < ef1) ? __builtin_nontemporal_load(&edq[ea])  : 0ULL;
            u64 qdb = (ex  < ef1) ? __builtin_nontemporal_load(&edq[ex])  : 0ULL;
            u64 qdc = (ea2 < ef1) ? __builtin_nontemporal_load(&edq[ea2]) : 0ULL;
            u64 qde = (ex2 < ef1) ? __builtin_nontemporal_load(&edq[ex2]) : 0ULL;
            int sa = (int)(qda & 0xffffffffULL), sb = (int)(qdb & 0xffffffffULL);
            int sc = (int)(qdc & 0xffffffffULL), se = (int)(qde & 0xffffffffULL);
            float wa = __uint_as_float((u32)(qda >> 32)) * dsf[sa];
            float wb = __uint_as_float((u32)(qdb >> 32)) * dsf[sb];
            float wc = __uint_as_float((u32)(qdc >> 32)) * dsf[sc];
            float we = __uint_as_float((u32)(qde >> 32)) * dsf[se];
            u64 qa = *(const u64*)(y1 + (((size_t)sa) << 6) + (fl << 2));
            u64 qb = *(const u64*)(y1 + (((size_t)sb) << 6) + (fl << 2));
            u64 qc = *(const u64*)(y1 + (((size_t)sc) << 6) + (fl << 2));
            u64 qe = *(const u64*)(y1 + (((size_t)se) << 6) + (fl << 2));
            f0 += wa * bf2f((u16)qa)         + wb * bf2f((u16)qb)
                + wc * bf2f((u16)qc)         + we * bf2f((u16)qe);
            f1 += wa * bf2f((u16)(qa >> 16)) + wb * bf2f((u16)(qb >> 16))
                + wc * bf2f((u16)(qc >> 16)) + we * bf2f((u16)(qe >> 16));
            f2 += wa * bf2f((u16)(qa >> 32)) + wb * bf2f((u16)(qb >> 32))
                + wc * bf2f((u16)(qc >> 32)) + we * bf2f((u16)(qe >> 32));
            f3 += wa * bf2f((u16)(qa >> 48)) + wb * bf2f((u16)(qb >> 48))
                + wc * bf2f((u16)(qc >> 48)) + we * bf2f((u16)(qe >> 48));
            ef += 16;
        }
        if (eb < eb1) {
            int ea = eb + g, ex = eb + 4 + g, ea2 = eb + 8 + g, ex2 = eb + 12 + g;
            u64 qda = (ea  < eb1) ? __builtin_nontemporal_load(&edq[ea])  : 0ULL;
            u64 qdb = (ex  < eb1) ? __builtin_nontemporal_load(&edq[ex])  : 0ULL;
            u64 qdc = (ea2 < eb1) ? __builtin_nontemporal_load(&edq[ea2]) : 0ULL;
            u64 qde = (ex2 < eb1) ? __builtin_nontemporal_load(&edq[ex2]) : 0ULL;
            int sa = (int)(qda & 0xffffffffULL), sb = (int)(qdb & 0xffffffffULL);
            int sc = (int)(qdc & 0xffffffffULL), se = (int)(qde & 0xffffffffULL);
            float wa = __uint_as_float((u32)(qda >> 32)) * dsb[sa];
            float wb = __uint_as_float((u32)(qdb >> 32)) * dsb[sb];
            float wc = __uint_as_float((u32)(qdc >> 32)) * dsb[sc];
            float we = __uint_as_float((u32)(qde >> 32)) * dsb[se];
            u64 qa = *(const u64*)(y2 + (((size_t)sa) << 6) + (fl << 2));
            u64 qb = *(const u64*)(y2 + (((size_t)sb) << 6) + (fl << 2));
            u64 qc = *(const u64*)(y2 + (((size_t)sc) << 6) + (fl << 2));
            u64 qe = *(const u64*)(y2 + (((size_t)se) << 6) + (fl << 2));
            b0 += wa * bf2f((u16)qa)         + wb * bf2f((u16)qb)
                + wc * bf2f((u16)qc)         + we * bf2f((u16)qe);
            b1 += wa * bf2f((u16)(qa >> 16)) + wb * bf2f((u16)(qb >> 16))
                + wc * bf2f((u16)(qc >> 16)) + we * bf2f((u16)(qe >> 16));
            b2 += wa * bf2f((u16)(qa >> 32)) + wb * bf2f((u16)(qb >> 32))
                + wc * bf2f((u16)(qc >> 32)) + we * bf2f((u16)(qe >> 32));
            b3 += wa * bf2f((u16)(qa >> 48)) + wb * bf2f((u16)(qb >> 48))
                + wc * bf2f((u16)(qc >> 48)) + we * bf2f((u16)(qe >> 48));
            eb += 16;
        }
    }
    float dout = dinv[node], din = dinv[N + node];
    float v0 = f0 * dout + b0 * din;
    float v1 = f1 * dout + b1 * din;
    float v2 = f2 * dout + b2 * din;
    float v3 = f3 * dout + b3 * din;
    v0 += __shfl_xor(v0, 16); v0 += __shfl_xor(v0, 32);
    v1 += __shfl_xor(v1, 16); v1 += __shfl_xor(v1, 32);
    v2 += __shfl_xor(v2, 16); v2 += __shfl_xor(v2, 32);
    v3 += __shfl_xor(v3, 16); v3 += __shfl_xor(v3, 32);
    if (g == 0) {
        float4 bs = *(const float4*)&b_src[fl << 2];
        float4 bd = *(const float4*)&b_dst[fl << 2];
        f32x4 o;
        o.x = v0 + ALPHA * bs.x + (1.f - ALPHA) * bd.x;
        o.y = v1 + ALPHA * bs.y + (1.f - ALPHA) * bd.y;
        o.z = v2 + ALPHA * bs.z + (1.f - ALPHA) * bd.z;
        o.w = v3 + ALPHA * bs.w + (1.f - ALPHA) * bd.w;
        __builtin_nontemporal_store(o, (f32x4*)&out[((size_t)node << 6) + (fl << 2)]);
    }
}

extern "C" void kernel_launch(void* const* d_in, const int* in_sizes, int n_in,
                              void* d_out, int out_size, void* d_ws, size_t ws_size,
                              hipStream_t stream) {
    const float* x     = (const float*)d_in[0];
    const int*   ei    = (const int*)d_in[1];
    const float* w     = (const float*)d_in[2];
    const float* W_src = (const float*)d_in[3];
    const float* b_src = (const float*)d_in[4];
    const float* W_dst = (const float*)d_in[5];
    const float* b_dst = (const float*)d_in[6];
    float* out = (float*)d_out;

    const int N = in_sizes[0] / D;
    const int E = in_sizes[2];
    const int* row = ei;
    const int* col = ei + E;
    const int L = 2 * N;
    const int NCH   = (E + CE - 1) / CE;          // chunks (782)
    const int NBUCK = (L + BN - 1) >> BSH;        // buckets (391), must be <= 512
    const int NT    = (N + 63) / 64;              // transform tiles (1563)

    // workspace layout (~86 MB)
    char* base = (char*)d_ws;
    size_t o = 0;
    auto take = [&](size_t b) { char* p = base + o; o = (o + b + 63) & ~(size_t)63; return p; };
    u32*    cursor = (u32*)take((size_t)NBUCK * 4);
    u64*    ent    = (u64*)take((size_t)NBUCK * CAP * 8);
    float*  dinv   = (float*)take((size_t)L * 4);
    int2*   ptr2   = (int2*)take((size_t)L * 8);
    u16*    y1     = (u16*)take((size_t)N * D * 2);
    u16*    y2     = (u16*)take((size_t)N * D * 2);
    float2* edata  = (float2*)take((size_t)NBUCK * CAP * 8);

    // 1. zero bucket cursors
    hipMemsetAsync(cursor, 0, (size_t)NBUCK * 4, stream);
    // 2. chunk-local counting sort into cursor-reserved padded buckets
    p3_sort_kernel<<<NCH, 512, 0, stream>>>(row, col, w, cursor, ent, N, E, NBUCK);
    // 3. fused: per-bucket build (streaming) + transform tiles (VALU) overlap
    p4_transform_kernel<<<NBUCK + NT, 512, 0, stream>>>(ent, cursor, dinv, ptr2, edata,
                                                        x, W_src, W_dst, y1, y2,
                                                        N, L, NBUCK, NT, NBUCK + NT);
    // 4. gather: dual-direction interleaved loop, NT edata loads, single out write
    gather_csr_kernel<<<(N + 3) / 4, 256, 0, stream>>>(ptr2, dinv, edata, y1, y2,
                                                       b_src, b_dst, out, N);
}

// Round 17
// 205.013 us; speedup vs baseline: 1.0566x; 1.0566x over previous
//
#include <hip/hip_runtime.h>

#define D 64
#define ALPHA 0.5f
#define FXSCALE 16777216.f   // 2^24 fixed-point quantum for degree accumulation
#define CE 2048              // edges per chunk (P3 block)
#define BSH 9                // log2(nodes per bucket)
#define BN 512               // nodes per bucket
#define CAP 9216             // padded bucket capacity (mean 8184, +11.5 sigma)

typedef unsigned long long u64;
typedef unsigned short u16;
typedef unsigned int u32;
typedef float f32x4 __attribute__((ext_vector_type(4)));

static __device__ __forceinline__ u16 f2bf(float f) {
    unsigned u = __float_as_uint(f);
    unsigned r = (u + 0x7fffu + ((u >> 16) & 1u)) >> 16;
    return (u16)r;
}
static __device__ __forceinline__ float bf2f(u16 h) {
    return __uint_as_float(((unsigned)h) << 16);
}
static __device__ __forceinline__ float dinv_of_fx(u32 fx) {
    float s = (float)fx * (1.f / FXSCALE);
    return (s > 0.f) ? rsqrtf(s) : 0.f;
}

// block-wide exclusive scan over 512 values using wave shuffles (2 barriers).
// in: v (per-thread). out: exclusive prefix. ws must be u32[8].
static __device__ __forceinline__ u32 block_exscan512(int t, u32 v, volatile u32* ws) {
    u32 p = v;
#pragma unroll
    for (int off = 1; off < 64; off <<= 1) {
        u32 u = __shfl_up((int)p, off);
        if ((t & 63) >= off) p += u;
    }                                   // p = inclusive prefix within wave
    int wv = t >> 6;
    if ((t & 63) == 63) ws[wv] = p;     // wave totals
    __syncthreads();
    u32 base = 0;
    if (wv > 0) {
#pragma unroll
        for (int i = 0; i < 7; ++i) if (i < wv) base += ws[i];
    }
    __syncthreads();
    return base + p - v;                // exclusive
}

// Fused heterogeneous kernel: P3 chunk-sort blocks + transform tiles.
// P3 role: in-LDS counting sort of a chunk's 2*CE entries by dst-bucket; one
// global atomicAdd per (chunk,bucket) reserves a run in the padded bucket
// region (base = bucket*CAP + cursor). entry u64 = w<<32 | src<<9 | dst_lo9.
// LDS union (u64 slots): ebuf[0,4096) ebkt[4096,5120) hcnt[5120,5376)
// hstart[5376,5632) hoff[5632,5888) hbase[5888,6144) ws[6144,6148)
// transform role: xs+Wt1+Wt2 = 12864 floats = 6432 u64.
__global__ __launch_bounds__(512)
void p3_transform_kernel(const int* __restrict__ row, const int* __restrict__ col,
                         const float* __restrict__ w, u32* __restrict__ cursor,
                         u64* __restrict__ ent,
                         const float* __restrict__ x,
                         const float* __restrict__ Ws, const float* __restrict__ Wd,
                         u16* __restrict__ y1, u16* __restrict__ y2,
                         int N, int E, int NCH, int NBUCK, int NT, int total_blocks) {
    __shared__ u64 smem[6432];
    int b = blockIdx.x;
    int t = threadIdx.x;
    // Bresenham spread: exactly NT transform blocks evenly interleaved
    int t_before = (int)(((long long)b * NT) / total_blocks);
    bool is_t = (int)(((long long)(b + 1) * NT) / total_blocks) > t_before;

    if (!is_t) {
        // ---------------- P3 sort role ----------------
        int ch = b - t_before;
        u64* ebuf   = smem;                    // [4096] u64
        u16* ebkt   = (u16*)(smem + 4096);     // [4096] u16
        u32* hcnt   = (u32*)(smem + 5120);     // [512]
        u32* hstart = (u32*)(smem + 5376);     // [512]
        u32* hoff   = (u32*)(smem + 5632);     // [512]
        u32* hbase  = (u32*)(smem + 5888);     // [512]
        u32* ws     = (u32*)(smem + 6144);     // [8]
        hcnt[t] = 0;
        __syncthreads();
        int e0 = ch * CE, e1 = min(E, e0 + CE);
        // phase 1: count per bucket
        for (int e = e0 + t; e < e1; e += 512) {
            atomicAdd(&hcnt[(u32)row[e] >> BSH], 1u);
            atomicAdd(&hcnt[(u32)(N + col[e]) >> BSH], 1u);
        }
        __syncthreads();
        // phase 2: exclusive scan (wave-shuffle, 2 barriers)
        u32 v = hcnt[t];
        u32 ex = block_exscan512(t, v, ws);
        hstart[t] = ex;
        hoff[t]   = ex;
        // phase 2b: reserve global run via one atomic per non-empty bucket
        u32 myb = 0;
        if (t < NBUCK && v > 0) myb = atomicAdd(&cursor[t], v);
        hbase[t] = myb;
        __syncthreads();
        // phase 3: place entries into LDS, bucket-grouped
        for (int e = e0 + t; e < e1; e += 512) {
            int r = row[e], c = col[e];
            u32 wb = __float_as_uint(w[e]);
            u32 b1 = (u32)r >> BSH;
            u64 q1 = ((u64)wb << 32) | ((u32)c << BSH) | ((u32)r & (BN - 1));
            u32 p1 = atomicAdd(&hoff[b1], 1u);
            ebuf[p1] = q1; ebkt[p1] = (u16)b1;
            u32 d2 = (u32)(N + c);
            u32 b2 = d2 >> BSH;
            u64 q2 = ((u64)wb << 32) | ((u32)r << BSH) | (d2 & (BN - 1));
            u32 p2 = atomicAdd(&hoff[b2], 1u);
            ebuf[p2] = q2; ebkt[p2] = (u16)b2;
        }
        __syncthreads();
        // phase 4: stream out — consecutive p within a bucket -> consecutive slots
        int nent = 2 * (e1 - e0);
        for (int p = t; p < nent; p += 512) {
            u32 bb = ebkt[p];
            u32 local = hbase[bb] + (u32)p - hstart[bb];
            if (local < CAP)   // overflow guard (statistically impossible)
                ent[(size_t)bb * CAP + local] = ebuf[p];
        }
        return;
    }

    // ---------------- transform role (64-row tile, 512 threads) ----------------
    float* xs  = (float*)smem;            // [64][65]
    float* Wt1 = xs + 64 * 65;            // [64][68] (272B row: float4-aligned)
    float* Wt2 = Wt1 + 64 * 68;
    for (int i = t; i < 4096; i += 512) {
        int o = i >> 6, k = i & 63;
        Wt1[k * 68 + o] = Ws[i];
        Wt2[k * 68 + o] = Wd[i];
    }
    int r0 = t_before * 64;
    for (int i = t; i < 4096; i += 512) {
        int r = i >> 6, k = i & 63;
        int gr = r0 + r;
        xs[r * 65 + k] = (gr < N) ? x[(size_t)gr * D + k] : 0.f;
    }
    __syncthreads();
    int ro = t >> 4, co = t & 15;        // ro 0..31 (2 rows each), co 0..15 (4 cols)
    float a1[2][4] = {}, a2[2][4] = {};
#pragma unroll 4
    for (int k = 0; k < 64; ++k) {
        float v0 = xs[(ro * 2 + 0) * 65 + k];
        float v1 = xs[(ro * 2 + 1) * 65 + k];
        float4 b1 = *(const float4*)&Wt1[k * 68 + co * 4];
        float4 b2 = *(const float4*)&Wt2[k * 68 + co * 4];
        a1[0][0] += v0 * b1.x; a1[0][1] += v0 * b1.y; a1[0][2] += v0 * b1.z; a1[0][3] += v0 * b1.w;
        a1[1][0] += v1 * b1.x; a1[1][1] += v1 * b1.y; a1[1][2] += v1 * b1.z; a1[1][3] += v1 * b1.w;
        a2[0][0] += v0 * b2.x; a2[0][1] += v0 * b2.y; a2[0][2] += v0 * b2.z; a2[0][3] += v0 * b2.w;
        a2[1][0] += v1 * b2.x; a2[1][1] += v1 * b2.y; a2[1][2] += v1 * b2.z; a2[1][3] += v1 * b2.w;
    }
#pragma unroll
    for (int i = 0; i < 2; ++i) {
        int gr = r0 + ro * 2 + i;
        if (gr < N) {
            ushort4 o1, o2;
            o1.x = f2bf(a1[i][0] * ALPHA); o1.y = f2bf(a1[i][1] * ALPHA);
            o1.z = f2bf(a1[i][2] * ALPHA); o1.w = f2bf(a1[i][3] * ALPHA);
            o2.x = f2bf(a2[i][0] * (1.f - ALPHA)); o2.y = f2bf(a2[i][1] * (1.f - ALPHA));
            o2.z = f2bf(a2[i][2] * (1.f - ALPHA)); o2.w = f2bf(a2[i][3] * (1.f - ALPHA));
            *(ushort4*)&y1[(size_t)gr * D + co * 4] = o1;
            *(ushort4*)&y2[(size_t)gr * D + co * 4] = o2;
        }
    }
}

// P4: per-bucket node histogram (counts + fixed-point weighted degree),
// per-node (start,end) -> ptr2, dinv, edata fill (src, w_raw).
__global__ void p4_build_kernel(const u64* __restrict__ ent, const u32* __restrict__ cursor,
                                float* __restrict__ dinv, int2* __restrict__ ptr2,
                                float2* __restrict__ edata,
                                int L, int NBUCK) {
    __shared__ u32 cnt[512], fx[512], pstart[512], pfill[512];
    __shared__ int s[512];
    int t = threadIdx.x, b = blockIdx.x;
    int base0 = b * CAP;
    int nE = min((int)cursor[b], CAP);
    cnt[t] = 0; fx[t] = 0;
    __syncthreads();
    for (int i = t; i < nE; i += 512) {
        u64 q = ent[(size_t)base0 + i];
        u32 dlo = (u32)q & (BN - 1);
        float wv = __uint_as_float((u32)(q >> 32));
        atomicAdd(&cnt[dlo], 1u);
        atomicAdd(&fx[dlo], (u32)__float2uint_rn(wv * FXSCALE));
    }
    __syncthreads();
    int v = (int)cnt[t];
    s[t] = v;
    __syncthreads();
    for (int off = 1; off < 512; off <<= 1) {
        int u = (t >= off) ? s[t - off] : 0;
        __syncthreads();
        s[t] += u;
        __syncthreads();
    }
    pstart[t] = (u32)(s[t] - v);
    pfill[t]  = (u32)(s[t] - v);
    int node = b * BN + t;
    if (node < L) {
        dinv[node] = dinv_of_fx(fx[t]);
        int st = base0 + (int)pstart[t];
        ptr2[node] = make_int2(st, st + v);
    }
    __syncthreads();
    for (int i = t; i < nE; i += 512) {
        u64 q = ent[(size_t)base0 + i];
        u32 dlo = (u32)q & (BN - 1);
        u32 src = ((u32)q) >> BSH;
        float wv = __uint_as_float((u32)(q >> 32));
        u32 pos = atomicAdd(&pfill[dlo], 1u);
        edata[(size_t)base0 + pos] = make_float2(__int_as_float((int)src), wv);
    }
}

// gather: one wave per node; 64 lanes = 4 edge-slots x 16 feature-slots.
// Both directions interleaved (8 independent chains). edata loaded
// NON-TEMPORAL (51 MB stream-once: don't evict reused y lines from L2).
__global__ void gather_csr_kernel(const int2* __restrict__ ptr2, const float* __restrict__ dinv,
                                  const float2* __restrict__ ed,
                                  const u16* __restrict__ y1, const u16* __restrict__ y2,
                                  const float* __restrict__ b_src, const float* __restrict__ b_dst,
                                  float* __restrict__ out, int N) {
    int tid = threadIdx.x;
    int lane = tid & 63;
    int node = blockIdx.x * (blockDim.x >> 6) + (tid >> 6);
    if (node >= N) return;
    int g  = lane >> 4;
    int fl = lane & 15;

    int2 pf = ptr2[node];          // fwd segment (y1)
    int2 pb = ptr2[N + node];      // bwd segment (y2)
    int ef = pf.x, ef1 = pf.y;
    int eb = pb.x, eb1 = pb.y;
    const float* __restrict__ dsf = dinv + N;   // fwd src-side dinv
    const float* __restrict__ dsb = dinv;       // bwd src-side dinv
    const u64* __restrict__ edq = (const u64*)ed;

    float f0 = 0.f, f1 = 0.f, f2 = 0.f, f3 = 0.f;
    float b0 = 0.f, b1 = 0.f, b2 = 0.f, b3 = 0.f;

    while (ef < ef1 || eb < eb1) {
        if (ef < ef1) {
            int ea = ef + g, ex = ef + 4 + g, ea2 = ef + 8 + g, ex2 = ef + 12 + g;
            u64 qda = (ea  < ef1) ? __builtin_nontemporal_load(&edq[ea])  : 0ULL;
            u64 qdb = (ex  < ef1) ? __builtin_nontemporal_load(&edq[ex])  : 0ULL;
            u64 qdc = (ea2 < ef1) ? __builtin_nontemporal_load(&edq[ea2]) : 0ULL;
            u64 qde = (ex2 < ef1) ? __builtin_nontemporal_load(&edq[ex2]) : 0ULL;
            int sa = (int)(qda & 0xffffffffULL), sb = (int)(qdb & 0xffffffffULL);
            int sc = (int)(qdc & 0xffffffffULL), se = (int)(qde & 0xffffffffULL);
            float wa = __uint_as_float((u32)(qda >> 32)) * dsf[sa];
            float wb = __uint_as_float((u32)(qdb >> 32)) * dsf[sb];
            float wc = __uint_as_float((u32)(qdc >> 32)) * dsf[sc];
            float we = __uint_as_float((u32)(qde >> 32)) * dsf[se];
            u64 qa = *(const u64*)(y1 + (((size_t)sa) << 6) + (fl << 2));
            u64 qb = *(const u64*)(y1 + (((size_t)sb) << 6) + (fl << 2));
            u64 qc = *(const u64*)(y1 + (((size_t)sc) << 6) + (fl << 2));
            u64 qe = *(const u64*)(y1 + (((size_t)se) << 6) + (fl << 2));
            f0 += wa * bf2f((u16)qa)         + wb * bf2f((u16)qb)
                + wc * bf2f((u16)qc)         + we * bf2f((u16)qe);
            f1 += wa * bf2f((u16)(qa >> 16)) + wb * bf2f((u16)(qb >> 16))
                + wc * bf2f((u16)(qc >> 16)) + we * bf2f((u16)(qe >> 16));
            f2 += wa * bf2f((u16)(qa >> 32)) + wb * bf2f((u16)(qb >> 32))
                + wc * bf2f((u16)(qc >> 32)) + we * bf2f((u16)(qe >> 32));
            f3 += wa * bf2f((u16)(qa >> 48)) + wb * bf2f((u16)(qb >> 48))
                + wc * bf2f((u16)(qc >> 48)) + we * bf2f((u16)(qe >> 48));
            ef += 16;
        }
        if (eb < eb1) {
            int ea = eb + g, ex = eb + 4 + g, ea2 = eb + 8 + g, ex2 = eb + 12 + g;
            u64 qda = (ea  < eb1) ? __builtin_nontemporal_load(&edq[ea])  : 0ULL;
            u64 qdb = (ex  < eb1) ? __builtin_nontemporal_load(&edq[ex])  : 0ULL;
            u64 qdc = (ea2 < eb1) ? __builtin_nontemporal_load(&edq[ea2]) : 0ULL;
            u64 qde = (ex2 < eb1) ? __builtin_nontemporal_load(&edq[ex2]) : 0ULL;
            int sa = (int)(qda & 0xffffffffULL), sb = (int)(qdb & 0xffffffffULL);
            int sc = (int)(qdc & 0xffffffffULL), se = (int)(qde & 0xffffffffULL);
            float wa = __uint_as_float((u32)(qda >> 32)) * dsb[sa];
            float wb = __uint_as_float((u32)(qdb >> 32)) * dsb[sb];
            float wc = __uint_as_float((u32)(qdc >> 32)) * dsb[sc];
            float we = __uint_as_float((u32)(qde >> 32)) * dsb[se];
            u64 qa = *(const u64*)(y2 + (((size_t)sa) << 6) + (fl << 2));
            u64 qb = *(const u64*)(y2 + (((size_t)sb) << 6) + (fl << 2));
            u64 qc = *(const u64*)(y2 + (((size_t)sc) << 6) + (fl << 2));
            u64 qe = *(const u64*)(y2 + (((size_t)se) << 6) + (fl << 2));
            b0 += wa * bf2f((u16)qa)         + wb * bf2f((u16)qb)
                + wc * bf2f((u16)qc)         + we * bf2f((u16)qe);
            b1 += wa * bf2f((u16)(qa >> 16)) + wb * bf2f((u16)(qb >> 16))
                + wc * bf2f((u16)(qc >> 16)) + we * bf2f((u16)(qe >> 16));
            b2 += wa * bf2f((u16)(qa >> 32)) + wb * bf2f((u16)(qb >> 32))
                + wc * bf2f((u16)(qc >> 32)) + we * bf2f((u16)(qe >> 32));
            b3 += wa * bf2f((u16)(qa >> 48)) + wb * bf2f((u16)(qb >> 48))
                + wc * bf2f((u16)(qc >> 48)) + we * bf2f((u16)(qe >> 48));
            eb += 16;
        }
    }
    float dout = dinv[node], din = dinv[N + node];
    float v0 = f0 * dout + b0 * din;
    float v1 = f1 * dout + b1 * din;
    float v2 = f2 * dout + b2 * din;
    float v3 = f3 * dout + b3 * din;
    v0 += __shfl_xor(v0, 16); v0 += __shfl_xor(v0, 32);
    v1 += __shfl_xor(v1, 16); v1 += __shfl_xor(v1, 32);
    v2 += __shfl_xor(v2, 16); v2 += __shfl_xor(v2, 32);
    v3 += __shfl_xor(v3, 16); v3 += __shfl_xor(v3, 32);
    if (g == 0) {
        float4 bs = *(const float4*)&b_src[fl << 2];
        float4 bd = *(const float4*)&b_dst[fl << 2];
        f32x4 o;
        o.x = v0 + ALPHA * bs.x + (1.f - ALPHA) * bd.x;
        o.y = v1 + ALPHA * bs.y + (1.f - ALPHA) * bd.y;
        o.z = v2 + ALPHA * bs.z + (1.f - ALPHA) * bd.z;
        o.w = v3 + ALPHA * bs.w + (1.f - ALPHA) * bd.w;
        __builtin_nontemporal_store(o, (f32x4*)&out[((size_t)node << 6) + (fl << 2)]);
    }
}

extern "C" void kernel_launch(void* const* d_in, const int* in_sizes, int n_in,
                              void* d_out, int out_size, void* d_ws, size_t ws_size,
                              hipStream_t stream) {
    const float* x     = (const float*)d_in[0];
    const int*   ei    = (const int*)d_in[1];
    const float* w     = (const float*)d_in[2];
    const float* W_src = (const float*)d_in[3];
    const float* b_src = (const float*)d_in[4];
    const float* W_dst = (const float*)d_in[5];
    const float* b_dst = (const float*)d_in[6];
    float* out = (float*)d_out;

    const int N = in_sizes[0] / D;
    const int E = in_sizes[2];
    const int* row = ei;
    const int* col = ei + E;
    const int L = 2 * N;
    const int NCH   = (E + CE - 1) / CE;          // chunks (782)
    const int NBUCK = (L + BN - 1) >> BSH;        // buckets (391), must be <= 512
    const int NT    = (N + 63) / 64;              // transform tiles (1563)

    // workspace layout (~86 MB)
    char* base = (char*)d_ws;
    size_t o = 0;
    auto take = [&](size_t b) { char* p = base + o; o = (o + b + 63) & ~(size_t)63; return p; };
    u32*    cursor = (u32*)take((size_t)NBUCK * 4);
    u64*    ent    = (u64*)take((size_t)NBUCK * CAP * 8);
    float*  dinv   = (float*)take((size_t)L * 4);
    int2*   ptr2   = (int2*)take((size_t)L * 8);
    u16*    y1     = (u16*)take((size_t)N * D * 2);
    u16*    y2     = (u16*)take((size_t)N * D * 2);
    float2* edata  = (float2*)take((size_t)NBUCK * CAP * 8);

    // 1. zero bucket cursors
    hipMemsetAsync(cursor, 0, (size_t)NBUCK * 4, stream);
    // 2. fused: chunk-local counting sort (cursor-reserved padded buckets)
    //    + transform tiles riding in the sort's latency shadow
    p3_transform_kernel<<<NCH + NT, 512, 0, stream>>>(row, col, w, cursor, ent,
                                                      x, W_src, W_dst, y1, y2,
                                                      N, E, NCH, NBUCK, NT, NCH + NT);
    // 3. per-bucket build -> dinv, ptr2, edata (L2-local scatter)
    p4_build_kernel<<<NBUCK, 512, 0, stream>>>(ent, cursor, dinv, ptr2, edata, L, NBUCK);
    // 4. gather: dual-direction interleaved loop, NT edata loads, single out write
    gather_csr_kernel<<<(N + 3) / 4, 256, 0, stream>>>(ptr2, dinv, edata, y1, y2,
                                                       b_src, b_dst, out, N);
}